// Round 1
// baseline (275.963 us; speedup 1.0000x reference)
//
#include <hip/hip_runtime.h>

#define NN 50000
#define NE 800000
#define D  64

// ---------------------------------------------------------------------------
// k1: deg[i] = 1.0 (self-loop)
__global__ void k_init_deg(float* __restrict__ deg) {
    int i = blockIdx.x * blockDim.x + threadIdx.x;
    if (i < NN) deg[i] = 1.0f;
}

// k2: deg[col[e]] += 1
__global__ void k_deg(const int* __restrict__ col, float* __restrict__ deg) {
    int i = blockIdx.x * blockDim.x + threadIdx.x;
    int stride = gridDim.x * blockDim.x;
    for (; i < NE; i += stride)
        atomicAdd(&deg[col[i]], 1.0f);
}

// k3: y[r][d] = (feat[r] . W[:,d]) * rsqrt(deg[r]); out[r][d] = y[r][d] (self loop)
__global__ __launch_bounds__(256) void k_gemm(const float* __restrict__ feat,
                                              const float* __restrict__ W,
                                              const float* __restrict__ deg,
                                              float* __restrict__ y,
                                              float* __restrict__ out) {
    __shared__ float Wlds[D * D];
    for (int i = threadIdx.x; i < D * D; i += blockDim.x) Wlds[i] = W[i];
    __syncthreads();

    const int lane   = threadIdx.x & 63;
    const int wave   = blockIdx.x * (blockDim.x >> 6) + (threadIdx.x >> 6);
    const int nwaves = gridDim.x * (blockDim.x >> 6);

    for (int r = wave; r < NN; r += nwaves) {
        float f = feat[r * D + lane];   // lane d holds feat[r][d]
        float acc = 0.0f;
        #pragma unroll
        for (int k = 0; k < D; ++k)
            acc = fmaf(__shfl(f, k), Wlds[k * D + lane], acc);
        float s = __frsqrt_rn(deg[r]);
        float v = acc * s;
        y[r * D + lane]   = v;
        out[r * D + lane] = v;          // self-loop contribution
    }
}

// k4: out[col[e]][d] += y[row[e]][d]   (wave-per-edge, lane=d)
__global__ __launch_bounds__(256) void k_scatter(const int* __restrict__ row,
                                                 const int* __restrict__ col,
                                                 const float* __restrict__ y,
                                                 float* __restrict__ out) {
    long long idx    = (long long)blockIdx.x * blockDim.x + threadIdx.x;
    long long stride = (long long)gridDim.x * blockDim.x;
    const long long total = (long long)NE * D;
    for (; idx < total; idx += stride) {
        int e = (int)(idx >> 6);
        int d = (int)(idx & 63);
        int r = row[e];   // uniform across the wave -> broadcast load
        int c = col[e];
        atomicAdd(&out[c * D + d], y[r * D + d]);
    }
}

// k5: out = out * rsqrt(deg[row]) + b   (float4 vectorized)
__global__ void k_final(float* __restrict__ out, const float* __restrict__ deg,
                        const float* __restrict__ b) {
    int i = blockIdx.x * blockDim.x + threadIdx.x;   // float4 index
    const int total = NN * D / 4;
    if (i >= total) return;
    int r  = i >> 4;            // 16 float4 per row
    int c4 = (i & 15) * 4;
    float s = __frsqrt_rn(deg[r]);
    float4 v = reinterpret_cast<float4*>(out)[i];
    v.x = v.x * s + b[c4 + 0];
    v.y = v.y * s + b[c4 + 1];
    v.z = v.z * s + b[c4 + 2];
    v.w = v.w * s + b[c4 + 3];
    reinterpret_cast<float4*>(out)[i] = v;
}

extern "C" void kernel_launch(void* const* d_in, const int* in_sizes, int n_in,
                              void* d_out, int out_size, void* d_ws, size_t ws_size,
                              hipStream_t stream) {
    const float* feat = (const float*)d_in[0];   // [NN, D]
    const float* W    = (const float*)d_in[1];   // [D, D]
    const float* b    = (const float*)d_in[2];   // [D]
    const int*   ei   = (const int*)d_in[3];     // [2, NE] row-major
    const int*   row  = ei;                      // sources
    const int*   col  = ei + NE;                 // targets

    float* out = (float*)d_out;                  // [NN, D]

    // workspace: deg (NN floats, padded to 65536) | y (NN*D floats)
    float* deg = (float*)d_ws;
    float* y   = (float*)d_ws + 65536;

    // 1. init deg
    k_init_deg<<<(NN + 255) / 256, 256, 0, stream>>>(deg);

    // 2. edge degree
    k_deg<<<(NE + 255) / 256, 256, 0, stream>>>(col, deg);

    // 3. fused gemm + pre-scale + self-loop init of out
    k_gemm<<<2048, 256, 0, stream>>>(feat, W, deg, y, out);

    // 4. scatter-add over edges
    k_scatter<<<4096, 256, 0, stream>>>(row, col, y, out);

    // 5. epilogue
    k_final<<<(NN * D / 4 + 255) / 256, 256, 0, stream>>>(out, deg, b);
}

// Round 2
// 174.993 us; speedup vs baseline: 1.5770x; 1.5770x over previous
//
#include <hip/hip_runtime.h>

#define NN 50000
#define NE 800000
#define D  64
#define NBLK ((NN + 255) / 256)   // 196 scan blocks

// ---------------------------------------------------------------------------
// k_count: cnt[col[e]] += 1  (int atomics; cnt pre-zeroed by hipMemsetAsync)
__global__ void k_count(const int* __restrict__ col, int* __restrict__ cnt) {
    int i = blockIdx.x * blockDim.x + threadIdx.x;
    if (i < NE) atomicAdd(&cnt[col[i]], 1);
}

// ---------------------------------------------------------------------------
// block-wide exclusive scan of one int per thread (256 threads = 4 waves)
__device__ inline int block_exscan(int val, int tid) {
    __shared__ int wsum[4];
    int lane = tid & 63, w = tid >> 6;
    int v = val;
    #pragma unroll
    for (int d = 1; d < 64; d <<= 1) {
        int t = __shfl_up(v, d);
        if (lane >= d) v += t;
    }
    if (lane == 63) wsum[w] = v;
    __syncthreads();
    int base = 0;
    #pragma unroll
    for (int i = 0; i < 4; ++i) base += (i < w) ? wsum[i] : 0;
    return base + v - val;   // exclusive
}

__global__ __launch_bounds__(256) void k_scan1(const int* __restrict__ cnt,
                                               int* __restrict__ off,
                                               int* __restrict__ bsum) {
    int tid = threadIdx.x;
    int i = blockIdx.x * 256 + tid;
    int val = (i < NN) ? cnt[i] : 0;
    int ex = block_exscan(val, tid);
    if (i < NN) off[i] = ex;
    if (tid == 255) bsum[blockIdx.x] = ex + val;
}

__global__ __launch_bounds__(256) void k_scan2(int* __restrict__ bsum) {
    int tid = threadIdx.x;
    int val = (tid < NBLK) ? bsum[tid] : 0;
    int ex = block_exscan(val, tid);
    if (tid < NBLK) bsum[tid] = ex;
}

__global__ __launch_bounds__(256) void k_scan3(int* __restrict__ off,
                                               int* __restrict__ cur,
                                               const int* __restrict__ bsum) {
    int i = blockIdx.x * 256 + threadIdx.x;
    if (i < NN) {
        int o = off[i] + bsum[blockIdx.x];
        off[i] = o;
        cur[i] = o;
    }
}

// ---------------------------------------------------------------------------
// k_fill: csr[cur[col[e]]++] = row[e]
__global__ void k_fill(const int* __restrict__ row, const int* __restrict__ col,
                       int* __restrict__ cur, int* __restrict__ csr) {
    int e = blockIdx.x * blockDim.x + threadIdx.x;
    if (e < NE) {
        int c = col[e];
        int p = atomicAdd(&cur[c], 1);
        csr[p] = row[e];
    }
}

// ---------------------------------------------------------------------------
// k_gemm: y[r][d] = (feat[r] . W[:,d]) * rsqrt(cnt[r]+1)
__global__ __launch_bounds__(256) void k_gemm(const float* __restrict__ feat,
                                              const float* __restrict__ W,
                                              const int* __restrict__ cnt,
                                              float* __restrict__ y) {
    __shared__ float Wlds[D * D];
    for (int i = threadIdx.x; i < D * D; i += blockDim.x) Wlds[i] = W[i];
    __syncthreads();

    const int lane   = threadIdx.x & 63;
    const int wave   = blockIdx.x * (blockDim.x >> 6) + (threadIdx.x >> 6);
    const int nwaves = gridDim.x * (blockDim.x >> 6);

    for (int r = wave; r < NN; r += nwaves) {
        float f = feat[r * D + lane];
        float acc = 0.0f;
        #pragma unroll
        for (int k = 0; k < D; ++k)
            acc = fmaf(__shfl(f, k), Wlds[k * D + lane], acc);
        float s = rsqrtf((float)cnt[r] + 1.0f);
        y[r * D + lane] = acc * s;
    }
}

// ---------------------------------------------------------------------------
// k_agg: out[c] = rsqrt(deg[c]) * (y[c] + sum_{e in csr[off[c]..]} y[csr[e]]) + b
// wave per node; 4 groups of 16 lanes, each group one edge, float4 per lane.
__global__ __launch_bounds__(256) void k_agg(const int* __restrict__ csr,
                                             const int* __restrict__ off,
                                             const int* __restrict__ cnt,
                                             const float* __restrict__ y,
                                             const float* __restrict__ b,
                                             float* __restrict__ out) {
    const int lane = threadIdx.x & 63;
    const int grp  = lane >> 4;        // 0..3: edge slot within wave
    const int l16  = lane & 15;        // float4 column index
    const int c    = blockIdx.x * (blockDim.x >> 6) + (threadIdx.x >> 6);
    if (c >= NN) return;

    const float4* y4 = reinterpret_cast<const float4*>(y);
    const float4  bb = reinterpret_cast<const float4*>(b)[l16];

    int s = off[c];
    int n = cnt[c];

    // self-loop contribution once (group 0 only)
    float4 acc = make_float4(0.f, 0.f, 0.f, 0.f);
    if (grp == 0) acc = y4[c * 16 + l16];

    for (int i = grp; i < n; i += 4) {
        int r = csr[s + i];
        float4 v = y4[r * 16 + l16];
        acc.x += v.x; acc.y += v.y; acc.z += v.z; acc.w += v.w;
    }

    // reduce across the 4 groups (butterfly over lane bits 4,5)
    acc.x += __shfl_xor(acc.x, 16); acc.y += __shfl_xor(acc.y, 16);
    acc.z += __shfl_xor(acc.z, 16); acc.w += __shfl_xor(acc.w, 16);
    acc.x += __shfl_xor(acc.x, 32); acc.y += __shfl_xor(acc.y, 32);
    acc.z += __shfl_xor(acc.z, 32); acc.w += __shfl_xor(acc.w, 32);

    if (grp == 0) {
        float sc = rsqrtf((float)n + 1.0f);
        float4 o;
        o.x = acc.x * sc + bb.x;
        o.y = acc.y * sc + bb.y;
        o.z = acc.z * sc + bb.z;
        o.w = acc.w * sc + bb.w;
        reinterpret_cast<float4*>(out)[c * 16 + l16] = o;
    }
}

// ---------------------------------------------------------------------------
extern "C" void kernel_launch(void* const* d_in, const int* in_sizes, int n_in,
                              void* d_out, int out_size, void* d_ws, size_t ws_size,
                              hipStream_t stream) {
    const float* feat = (const float*)d_in[0];   // [NN, D]
    const float* W    = (const float*)d_in[1];   // [D, D]
    const float* b    = (const float*)d_in[2];   // [D]
    const int*   ei   = (const int*)d_in[3];     // [2, NE]
    const int*   row  = ei;                      // sources
    const int*   col  = ei + NE;                 // targets

    float* out = (float*)d_out;                  // [NN, D]

    // workspace layout (16.8 MB)
    int*   cnt  = (int*)d_ws;            // [65536]
    int*   off  = cnt + 65536;           // [65536]
    int*   cur  = off + 65536;           // [65536]
    int*   bsum = cur + 65536;           // [1024]
    int*   csr  = bsum + 1024;           // [802816]
    float* y    = (float*)(csr + 802816); // [NN*D], 16B-aligned

    hipMemsetAsync(cnt, 0, NN * sizeof(int), stream);

    k_count<<<(NE + 255) / 256, 256, 0, stream>>>(col, cnt);
    k_scan1<<<NBLK, 256, 0, stream>>>(cnt, off, bsum);
    k_scan2<<<1, 256, 0, stream>>>(bsum);
    k_scan3<<<NBLK, 256, 0, stream>>>(off, cur, bsum);
    k_fill<<<(NE + 255) / 256, 256, 0, stream>>>(row, col, cur, csr);
    k_gemm<<<2048, 256, 0, stream>>>(feat, W, cnt, y);
    k_agg<<<(NN + 3) / 4, 256, 0, stream>>>(csr, off, cnt, y, b, out);
}

// Round 3
// 164.073 us; speedup vs baseline: 1.6819x; 1.0666x over previous
//
#include <hip/hip_runtime.h>
#include <hip/hip_fp16.h>

#define NN 50000
#define NE 800000
#define D  64
#define NBLK ((NN + 255) / 256)   // 196 scan blocks

// ---------------------------------------------------------------------------
// k_count: cnt[col[e]] += 1  (cnt pre-zeroed by hipMemsetAsync)
__global__ void k_count(const int* __restrict__ col, int* __restrict__ cnt) {
    int i = blockIdx.x * blockDim.x + threadIdx.x;
    if (i < NE) atomicAdd(&cnt[col[i]], 1);
}

// ---------------------------------------------------------------------------
// block-wide exclusive scan of one int per thread (256 threads = 4 waves)
__device__ inline int block_exscan(int val, int tid) {
    __shared__ int wsum[4];
    int lane = tid & 63, w = tid >> 6;
    int v = val;
    #pragma unroll
    for (int d = 1; d < 64; d <<= 1) {
        int t = __shfl_up(v, d);
        if (lane >= d) v += t;
    }
    if (lane == 63) wsum[w] = v;
    __syncthreads();
    int base = 0;
    #pragma unroll
    for (int i = 0; i < 4; ++i) base += (i < w) ? wsum[i] : 0;
    return base + v - val;   // exclusive
}

__global__ __launch_bounds__(256) void k_scan1(const int* __restrict__ cnt,
                                               int* __restrict__ off,
                                               int* __restrict__ bsum) {
    int tid = threadIdx.x;
    int i = blockIdx.x * 256 + tid;
    int val = (i < NN) ? cnt[i] : 0;
    int ex = block_exscan(val, tid);
    if (i < NN) off[i] = ex;
    if (tid == 255) bsum[blockIdx.x] = ex + val;
}

__global__ __launch_bounds__(256) void k_scan2(int* __restrict__ bsum) {
    int tid = threadIdx.x;
    int val = (tid < NBLK) ? bsum[tid] : 0;
    int ex = block_exscan(val, tid);
    if (tid < NBLK) bsum[tid] = ex;
}

__global__ __launch_bounds__(256) void k_scan3(int* __restrict__ off,
                                               int* __restrict__ cur,
                                               const int* __restrict__ bsum) {
    int i = blockIdx.x * 256 + threadIdx.x;
    if (i < NN) {
        int o = off[i] + bsum[blockIdx.x];
        off[i] = o;
        cur[i] = o;
    }
}

// ---------------------------------------------------------------------------
// k_fill: csr[cur[col[e]]++] = (ushort)row[e]
__global__ void k_fill(const int* __restrict__ row, const int* __restrict__ col,
                       int* __restrict__ cur, unsigned short* __restrict__ csr) {
    int e = blockIdx.x * blockDim.x + threadIdx.x;
    if (e < NE) {
        int c = col[e];
        int p = atomicAdd(&cur[c], 1);
        csr[p] = (unsigned short)row[e];
    }
}

// ---------------------------------------------------------------------------
// k_gemm: y[r][d] = fp16( (feat[r] . W[:,d]) * rsqrt(cnt[r]+1) )
__global__ __launch_bounds__(256) void k_gemm(const float* __restrict__ feat,
                                              const float* __restrict__ W,
                                              const int* __restrict__ cnt,
                                              __half* __restrict__ y) {
    __shared__ float Wlds[D * D];
    for (int i = threadIdx.x; i < D * D; i += blockDim.x) Wlds[i] = W[i];
    __syncthreads();

    const int lane   = threadIdx.x & 63;
    const int wave   = blockIdx.x * (blockDim.x >> 6) + (threadIdx.x >> 6);
    const int nwaves = gridDim.x * (blockDim.x >> 6);

    for (int r = wave; r < NN; r += nwaves) {
        float f = feat[r * D + lane];
        float acc = 0.0f;
        #pragma unroll
        for (int k = 0; k < D; ++k)
            acc = fmaf(__shfl(f, k), Wlds[k * D + lane], acc);
        float s = rsqrtf((float)cnt[r] + 1.0f);
        y[r * D + lane] = __float2half(acc * s);
    }
}

// ---------------------------------------------------------------------------
// k_agg: out[c] = rsqrt(deg[c]) * (y[c] + sum_{i} y[csr[off[c]+i]]) + b
// wave per node; 8 groups of 8 lanes; each lane loads 16B = 8 halfs.
__global__ __launch_bounds__(256) void k_agg(const unsigned short* __restrict__ csr,
                                             const int* __restrict__ off,
                                             const int* __restrict__ cnt,
                                             const __half* __restrict__ y,
                                             const float* __restrict__ b,
                                             float* __restrict__ out) {
    const int lane = threadIdx.x & 63;
    const int grp  = lane >> 3;        // 0..7: edge slot within wave
    const int l8   = lane & 7;         // 16B column block within the row
    const int c    = blockIdx.x * (blockDim.x >> 6) + (threadIdx.x >> 6);
    if (c >= NN) return;

    const uint4* y16 = reinterpret_cast<const uint4*>(y);   // 8 halfs per uint4

    int s = off[c];
    int n = cnt[c];

    float acc[8] = {0.f, 0.f, 0.f, 0.f, 0.f, 0.f, 0.f, 0.f};

    auto addrow = [&](int r) {
        uint4 u = y16[r * 8 + l8];
        const __half2* h = reinterpret_cast<const __half2*>(&u);
        float2 f0 = __half22float2(h[0]);
        float2 f1 = __half22float2(h[1]);
        float2 f2 = __half22float2(h[2]);
        float2 f3 = __half22float2(h[3]);
        acc[0] += f0.x; acc[1] += f0.y; acc[2] += f1.x; acc[3] += f1.y;
        acc[4] += f2.x; acc[5] += f2.y; acc[6] += f3.x; acc[7] += f3.y;
    };

    if (grp == 0) addrow(c);                      // self-loop
    for (int i = grp; i < n; i += 8) addrow(csr[s + i]);

    // reduce across the 8 groups (butterfly over lane bits 3,4,5)
    #pragma unroll
    for (int m = 8; m <= 32; m <<= 1) {
        #pragma unroll
        for (int j = 0; j < 8; ++j) acc[j] += __shfl_xor(acc[j], m);
    }

    if (grp == 0) {
        float sc = rsqrtf((float)n + 1.0f);
        const float4* b4 = reinterpret_cast<const float4*>(b);
        float4 bb0 = b4[l8 * 2], bb1 = b4[l8 * 2 + 1];
        float4 o0, o1;
        o0.x = acc[0] * sc + bb0.x;  o0.y = acc[1] * sc + bb0.y;
        o0.z = acc[2] * sc + bb0.z;  o0.w = acc[3] * sc + bb0.w;
        o1.x = acc[4] * sc + bb1.x;  o1.y = acc[5] * sc + bb1.y;
        o1.z = acc[6] * sc + bb1.z;  o1.w = acc[7] * sc + bb1.w;
        float4* out4 = reinterpret_cast<float4*>(out);
        out4[c * 16 + l8 * 2]     = o0;
        out4[c * 16 + l8 * 2 + 1] = o1;
    }
}

// ---------------------------------------------------------------------------
extern "C" void kernel_launch(void* const* d_in, const int* in_sizes, int n_in,
                              void* d_out, int out_size, void* d_ws, size_t ws_size,
                              hipStream_t stream) {
    const float* feat = (const float*)d_in[0];   // [NN, D]
    const float* W    = (const float*)d_in[1];   // [D, D]
    const float* b    = (const float*)d_in[2];   // [D]
    const int*   ei   = (const int*)d_in[3];     // [2, NE]
    const int*   row  = ei;                      // sources
    const int*   col  = ei + NE;                 // targets

    float* out = (float*)d_out;                  // [NN, D]

    // workspace layout (~8.8 MB)
    int*            cnt  = (int*)d_ws;             // [65536]
    int*            off  = cnt + 65536;            // [65536]
    int*            cur  = off + 65536;            // [65536]
    int*            bsum = cur + 65536;            // [1024]
    unsigned short* csr  = (unsigned short*)(bsum + 1024);   // [802816]
    __half*         y    = (__half*)(csr + 802816);          // [NN*D], 16B-aligned

    hipMemsetAsync(cnt, 0, NN * sizeof(int), stream);

    k_count<<<(NE + 255) / 256, 256, 0, stream>>>(col, cnt);
    k_scan1<<<NBLK, 256, 0, stream>>>(cnt, off, bsum);
    k_scan2<<<1, 256, 0, stream>>>(bsum);
    k_scan3<<<NBLK, 256, 0, stream>>>(off, cur, bsum);
    k_fill<<<(NE + 255) / 256, 256, 0, stream>>>(row, col, cur, csr);
    k_gemm<<<2048, 256, 0, stream>>>(feat, W, cnt, y);
    k_agg<<<(NN + 3) / 4, 256, 0, stream>>>(csr, off, cnt, y, b, out);
}

// Round 4
// 133.717 us; speedup vs baseline: 2.0638x; 1.2270x over previous
//
#include <hip/hip_runtime.h>
#include <hip/hip_fp16.h>

#define NN 50000
#define NE 800000
#define D  64
#define NBLK ((NN + 255) / 256)   // 196 scan blocks
#define FS 68                      // feat LDS stride (pad 64 -> 68 = 4*17)

// ---------------------------------------------------------------------------
// k_count: cnt[col[e]] += 1  (cnt pre-zeroed by hipMemsetAsync)
__global__ void k_count(const int* __restrict__ col, int* __restrict__ cnt) {
    int i = blockIdx.x * blockDim.x + threadIdx.x;
    if (i < NE) atomicAdd(&cnt[col[i]], 1);
}

// ---------------------------------------------------------------------------
// block-wide exclusive scan of one int per thread (256 threads = 4 waves)
__device__ inline int block_exscan(int val, int tid) {
    __shared__ int wsum[4];
    int lane = tid & 63, w = tid >> 6;
    int v = val;
    #pragma unroll
    for (int d = 1; d < 64; d <<= 1) {
        int t = __shfl_up(v, d);
        if (lane >= d) v += t;
    }
    if (lane == 63) wsum[w] = v;
    __syncthreads();
    int base = 0;
    #pragma unroll
    for (int i = 0; i < 4; ++i) base += (i < w) ? wsum[i] : 0;
    return base + v - val;   // exclusive
}

__global__ __launch_bounds__(256) void k_scan1(const int* __restrict__ cnt,
                                               int* __restrict__ off,
                                               int* __restrict__ bsum) {
    int tid = threadIdx.x;
    int i = blockIdx.x * 256 + tid;
    int val = (i < NN) ? cnt[i] : 0;
    int ex = block_exscan(val, tid);
    if (i < NN) off[i] = ex;
    if (tid == 255) bsum[blockIdx.x] = ex + val;
}

__global__ __launch_bounds__(256) void k_scan2(int* __restrict__ bsum) {
    int tid = threadIdx.x;
    int val = (tid < NBLK) ? bsum[tid] : 0;
    int ex = block_exscan(val, tid);
    if (tid < NBLK) bsum[tid] = ex;
}

__global__ __launch_bounds__(256) void k_scan3(int* __restrict__ off,
                                               int* __restrict__ cur,
                                               const int* __restrict__ bsum) {
    int i = blockIdx.x * 256 + threadIdx.x;
    if (i < NN) {
        int o = off[i] + bsum[blockIdx.x];
        off[i] = o;
        cur[i] = o;
    }
}

// ---------------------------------------------------------------------------
// k_fill: csr[cur[col[e]]++] = (ushort)row[e]
__global__ void k_fill(const int* __restrict__ row, const int* __restrict__ col,
                       int* __restrict__ cur, unsigned short* __restrict__ csr) {
    int e = blockIdx.x * blockDim.x + threadIdx.x;
    if (e < NE) {
        int c = col[e];
        int p = atomicAdd(&cur[c], 1);
        csr[p] = (unsigned short)row[e];
    }
}

// ---------------------------------------------------------------------------
// k_gemm: y[r][d] = fp16( (feat[r] . W[:,d]) * rsqrt(cnt[r]+1) )
// LDS-tiled, 64 rows/block, 4x4 register tile per thread.
__global__ __launch_bounds__(256) void k_gemm(const float* __restrict__ feat,
                                              const float* __restrict__ W,
                                              const int* __restrict__ cnt,
                                              __half* __restrict__ y) {
    __shared__ float feat_lds[64 * FS];
    __shared__ float W_lds[D * D];

    const int tid   = threadIdx.x;
    const int rbase = blockIdx.x * 64;

    // stage W (coalesced float4 copy)
    {
        const float4* W4  = reinterpret_cast<const float4*>(W);
        float4*       Wl4 = reinterpret_cast<float4*>(W_lds);
        for (int i = tid; i < D * D / 4; i += 256) Wl4[i] = W4[i];
    }
    // stage feat tile: 4 iters x 16 rows, float4 per thread
    {
        const int k0 = (tid & 15) * 4;
        #pragma unroll
        for (int it = 0; it < 4; ++it) {
            int r  = it * 16 + (tid >> 4);
            int gr = rbase + r;
            float4 v = make_float4(0.f, 0.f, 0.f, 0.f);
            if (gr < NN) v = *reinterpret_cast<const float4*>(&feat[gr * D + k0]);
            *reinterpret_cast<float4*>(&feat_lds[r * FS + k0]) = v;
        }
    }
    __syncthreads();

    const int tx = tid & 15;    // col group: d = tx*4 .. tx*4+3
    const int ty = tid >> 4;    // row group: r = ty*4 .. ty*4+3

    float acc[4][4] = {};

    #pragma unroll 8
    for (int k = 0; k < D; ++k) {
        float4 w = *reinterpret_cast<const float4*>(&W_lds[k * D + tx * 4]);
        float f0 = feat_lds[(ty * 4 + 0) * FS + k];
        float f1 = feat_lds[(ty * 4 + 1) * FS + k];
        float f2 = feat_lds[(ty * 4 + 2) * FS + k];
        float f3 = feat_lds[(ty * 4 + 3) * FS + k];
        acc[0][0] = fmaf(f0, w.x, acc[0][0]); acc[0][1] = fmaf(f0, w.y, acc[0][1]);
        acc[0][2] = fmaf(f0, w.z, acc[0][2]); acc[0][3] = fmaf(f0, w.w, acc[0][3]);
        acc[1][0] = fmaf(f1, w.x, acc[1][0]); acc[1][1] = fmaf(f1, w.y, acc[1][1]);
        acc[1][2] = fmaf(f1, w.z, acc[1][2]); acc[1][3] = fmaf(f1, w.w, acc[1][3]);
        acc[2][0] = fmaf(f2, w.x, acc[2][0]); acc[2][1] = fmaf(f2, w.y, acc[2][1]);
        acc[2][2] = fmaf(f2, w.z, acc[2][2]); acc[2][3] = fmaf(f2, w.w, acc[2][3]);
        acc[3][0] = fmaf(f3, w.x, acc[3][0]); acc[3][1] = fmaf(f3, w.y, acc[3][1]);
        acc[3][2] = fmaf(f3, w.z, acc[3][2]); acc[3][3] = fmaf(f3, w.w, acc[3][3]);
    }

    #pragma unroll
    for (int i = 0; i < 4; ++i) {
        int gr = rbase + ty * 4 + i;
        if (gr < NN) {
            float s = rsqrtf((float)cnt[gr] + 1.0f);
            __half2 h0 = __floats2half2_rn(acc[i][0] * s, acc[i][1] * s);
            __half2 h1 = __floats2half2_rn(acc[i][2] * s, acc[i][3] * s);
            union { __half2 h[2]; uint2 u; } p;
            p.h[0] = h0; p.h[1] = h1;
            *reinterpret_cast<uint2*>(&y[gr * D + tx * 4]) = p.u;
        }
    }
}

// ---------------------------------------------------------------------------
// k_agg: out[c] = rsqrt(deg[c]) * (y[c] + sum_{i} y[csr[off[c]+i]]) + b
// wave per node; 8 groups of 8 lanes; each lane loads 16B = 8 halfs.
__global__ __launch_bounds__(256) void k_agg(const unsigned short* __restrict__ csr,
                                             const int* __restrict__ off,
                                             const int* __restrict__ cnt,
                                             const __half* __restrict__ y,
                                             const float* __restrict__ b,
                                             float* __restrict__ out) {
    const int lane = threadIdx.x & 63;
    const int grp  = lane >> 3;        // 0..7: edge slot within wave
    const int l8   = lane & 7;         // 16B column block within the row
    const int c    = blockIdx.x * (blockDim.x >> 6) + (threadIdx.x >> 6);
    if (c >= NN) return;

    const uint4* y16 = reinterpret_cast<const uint4*>(y);   // 8 halfs per uint4

    int s = off[c];
    int n = cnt[c];

    float acc[8] = {0.f, 0.f, 0.f, 0.f, 0.f, 0.f, 0.f, 0.f};

    auto addrow = [&](int r) {
        uint4 u = y16[r * 8 + l8];
        const __half2* h = reinterpret_cast<const __half2*>(&u);
        float2 f0 = __half22float2(h[0]);
        float2 f1 = __half22float2(h[1]);
        float2 f2 = __half22float2(h[2]);
        float2 f3 = __half22float2(h[3]);
        acc[0] += f0.x; acc[1] += f0.y; acc[2] += f1.x; acc[3] += f1.y;
        acc[4] += f2.x; acc[5] += f2.y; acc[6] += f3.x; acc[7] += f3.y;
    };

    if (grp == 0) addrow(c);                      // self-loop
    for (int i = grp; i < n; i += 8) addrow(csr[s + i]);

    // reduce across the 8 groups (butterfly over lane bits 3,4,5)
    #pragma unroll
    for (int m = 8; m <= 32; m <<= 1) {
        #pragma unroll
        for (int j = 0; j < 8; ++j) acc[j] += __shfl_xor(acc[j], m);
    }

    if (grp == 0) {
        float sc = rsqrtf((float)n + 1.0f);
        const float4* b4 = reinterpret_cast<const float4*>(b);
        float4 bb0 = b4[l8 * 2], bb1 = b4[l8 * 2 + 1];
        float4 o0, o1;
        o0.x = acc[0] * sc + bb0.x;  o0.y = acc[1] * sc + bb0.y;
        o0.z = acc[2] * sc + bb0.z;  o0.w = acc[3] * sc + bb0.w;
        o1.x = acc[4] * sc + bb1.x;  o1.y = acc[5] * sc + bb1.y;
        o1.z = acc[6] * sc + bb1.z;  o1.w = acc[7] * sc + bb1.w;
        float4* out4 = reinterpret_cast<float4*>(out);
        out4[c * 16 + l8 * 2]     = o0;
        out4[c * 16 + l8 * 2 + 1] = o1;
    }
}

// ---------------------------------------------------------------------------
extern "C" void kernel_launch(void* const* d_in, const int* in_sizes, int n_in,
                              void* d_out, int out_size, void* d_ws, size_t ws_size,
                              hipStream_t stream) {
    const float* feat = (const float*)d_in[0];   // [NN, D]
    const float* W    = (const float*)d_in[1];   // [D, D]
    const float* b    = (const float*)d_in[2];   // [D]
    const int*   ei   = (const int*)d_in[3];     // [2, NE]
    const int*   row  = ei;                      // sources
    const int*   col  = ei + NE;                 // targets

    float* out = (float*)d_out;                  // [NN, D]

    // workspace layout (~8.8 MB)
    int*            cnt  = (int*)d_ws;             // [65536]
    int*            off  = cnt + 65536;            // [65536]
    int*            cur  = off + 65536;            // [65536]
    int*            bsum = cur + 65536;            // [1024]
    unsigned short* csr  = (unsigned short*)(bsum + 1024);   // [802816]
    __half*         y    = (__half*)(csr + 802816);          // [NN*D], 16B-aligned

    hipMemsetAsync(cnt, 0, NN * sizeof(int), stream);

    k_count<<<(NE + 255) / 256, 256, 0, stream>>>(col, cnt);
    k_scan1<<<NBLK, 256, 0, stream>>>(cnt, off, bsum);
    k_scan2<<<1, 256, 0, stream>>>(bsum);
    k_scan3<<<NBLK, 256, 0, stream>>>(off, cur, bsum);
    k_fill<<<(NE + 255) / 256, 256, 0, stream>>>(row, col, cur, csr);
    k_gemm<<<(NN + 63) / 64, 256, 0, stream>>>(feat, W, cnt, y);
    k_agg<<<(NN + 3) / 4, 256, 0, stream>>>(csr, off, cnt, y, b, out);
}

// Round 5
// 68.667 us; speedup vs baseline: 4.0188x; 1.9473x over previous
//
#include <hip/hip_runtime.h>
#include <hip/hip_fp16.h>

#define NN 50000
#define NE 800000
#define D  64
#define NBUK 256
#define CHUNK (NE / NBUK)   // 3125 exactly
#define FS 68               // feat LDS stride (pad 64 -> 68)

// ---------------------------------------------------------------------------
// block-wide exclusive scan of one int per thread (256 threads = 4 waves).
// Trailing sync so it is safe to call repeatedly (shared wsum reuse).
__device__ inline int block_exscan(int val, int tid) {
    __shared__ int wsum[4];
    int lane = tid & 63, w = tid >> 6;
    int v = val;
    #pragma unroll
    for (int d = 1; d < 64; d <<= 1) {
        int t = __shfl_up(v, d);
        if (lane >= d) v += t;
    }
    if (lane == 63) wsum[w] = v;
    __syncthreads();
    int base = 0;
    #pragma unroll
    for (int i = 0; i < 4; ++i) base += (i < w) ? wsum[i] : 0;
    __syncthreads();
    return base + v - val;   // exclusive
}

// ---------------------------------------------------------------------------
// pass A: per-block LDS histogram over buckets (col>>8). H is bucket-major.
__global__ __launch_bounds__(256) void k_hist(const int* __restrict__ col,
                                              int* __restrict__ H) {
    __shared__ int h[NBUK];
    const int tid = threadIdx.x, blk = blockIdx.x;
    h[tid] = 0;
    __syncthreads();
    const int base = blk * CHUNK;
    for (int i = tid; i < CHUNK; i += 256)
        atomicAdd(&h[col[base + i] >> 8], 1);
    __syncthreads();
    H[tid * NBUK + blk] = h[tid];
}

// pass B: scan H in place. Block j covers bucket j; bsum[j] = bucket total.
__global__ __launch_bounds__(256) void k_scanA(int* __restrict__ H,
                                               int* __restrict__ bsum) {
    const int tid = threadIdx.x, blk = blockIdx.x;
    const int i = blk * 256 + tid;
    int val = H[i];
    int ex = block_exscan(val, tid);
    H[i] = ex;
    if (tid == 255) bsum[blk] = ex + val;
}

// pass C: scatter edges into bucket segments as packed (row | (col&255)<<16)
__global__ __launch_bounds__(256) void k_bucket(const int* __restrict__ row,
                                                const int* __restrict__ col,
                                                const int* __restrict__ H,
                                                const int* __restrict__ bsum,
                                                unsigned int* __restrict__ packed) {
    __shared__ int base_l[NBUK];
    __shared__ int rank[NBUK];
    const int tid = threadIdx.x, blk = blockIdx.x;
    int ex = block_exscan(bsum[tid], tid);      // global bucket base
    base_l[tid] = ex + H[tid * NBUK + blk];     // + this block's chunk offset
    rank[tid] = 0;
    __syncthreads();
    const int base = blk * CHUNK;
    for (int i = tid; i < CHUNK; i += 256) {
        int c = col[base + i], r = row[base + i];
        int bk = c >> 8;
        int rk = atomicAdd(&rank[bk], 1);
        packed[base_l[bk] + rk] =
            (unsigned)(r & 0xFFFF) | ((unsigned)(c & 0xFF) << 16);
    }
}

// pass D: per-bucket CSR finalize: off/cnt per node + csr ushort rows.
// All csr writes land in this block's private segment (no XCD ping-pong).
__global__ __launch_bounds__(256) void k_csr(const unsigned int* __restrict__ packed,
                                             const int* __restrict__ bsum,
                                             int* __restrict__ off,
                                             int* __restrict__ cnt,
                                             unsigned short* __restrict__ csr) {
    __shared__ int exs[NBUK];
    __shared__ int ncnt[NBUK];
    __shared__ int nbase[NBUK];
    __shared__ int rk2[NBUK];
    const int tid = threadIdx.x, b = blockIdx.x;
    int ex = block_exscan(bsum[tid], tid);
    exs[tid] = ex;
    ncnt[tid] = 0;
    rk2[tid] = 0;
    __syncthreads();
    const int start = exs[b];
    const int size  = bsum[b];
    for (int i = tid; i < size; i += 256)
        atomicAdd(&ncnt[(packed[start + i] >> 16) & 0xFF], 1);
    __syncthreads();
    int v2  = ncnt[tid];
    int ex2 = block_exscan(v2, tid);
    const int node = b * NBUK + tid;
    off[node] = start + ex2;
    cnt[node] = v2;
    nbase[tid] = start + ex2;
    __syncthreads();
    for (int i = tid; i < size; i += 256) {
        unsigned u = packed[start + i];
        int ln = (u >> 16) & 0xFF;
        int rk = atomicAdd(&rk2[ln], 1);
        csr[nbase[ln] + rk] = (unsigned short)(u & 0xFFFF);
    }
}

// ---------------------------------------------------------------------------
// k_gemm: y[r][d] = fp16( (feat[r] . W[:,d]) * rsqrt(cnt[r]+1) )
__global__ __launch_bounds__(256) void k_gemm(const float* __restrict__ feat,
                                              const float* __restrict__ W,
                                              const int* __restrict__ cnt,
                                              __half* __restrict__ y) {
    __shared__ float feat_lds[64 * FS];
    __shared__ float W_lds[D * D];

    const int tid   = threadIdx.x;
    const int rbase = blockIdx.x * 64;

    {
        const float4* W4  = reinterpret_cast<const float4*>(W);
        float4*       Wl4 = reinterpret_cast<float4*>(W_lds);
        for (int i = tid; i < D * D / 4; i += 256) Wl4[i] = W4[i];
    }
    {
        const int k0 = (tid & 15) * 4;
        #pragma unroll
        for (int it = 0; it < 4; ++it) {
            int r  = it * 16 + (tid >> 4);
            int gr = rbase + r;
            float4 v = make_float4(0.f, 0.f, 0.f, 0.f);
            if (gr < NN) v = *reinterpret_cast<const float4*>(&feat[gr * D + k0]);
            *reinterpret_cast<float4*>(&feat_lds[r * FS + k0]) = v;
        }
    }
    __syncthreads();

    const int tx = tid & 15;
    const int ty = tid >> 4;

    float acc[4][4] = {};

    #pragma unroll 8
    for (int k = 0; k < D; ++k) {
        float4 w = *reinterpret_cast<const float4*>(&W_lds[k * D + tx * 4]);
        float f0 = feat_lds[(ty * 4 + 0) * FS + k];
        float f1 = feat_lds[(ty * 4 + 1) * FS + k];
        float f2 = feat_lds[(ty * 4 + 2) * FS + k];
        float f3 = feat_lds[(ty * 4 + 3) * FS + k];
        acc[0][0] = fmaf(f0, w.x, acc[0][0]); acc[0][1] = fmaf(f0, w.y, acc[0][1]);
        acc[0][2] = fmaf(f0, w.z, acc[0][2]); acc[0][3] = fmaf(f0, w.w, acc[0][3]);
        acc[1][0] = fmaf(f1, w.x, acc[1][0]); acc[1][1] = fmaf(f1, w.y, acc[1][1]);
        acc[1][2] = fmaf(f1, w.z, acc[1][2]); acc[1][3] = fmaf(f1, w.w, acc[1][3]);
        acc[2][0] = fmaf(f2, w.x, acc[2][0]); acc[2][1] = fmaf(f2, w.y, acc[2][1]);
        acc[2][2] = fmaf(f2, w.z, acc[2][2]); acc[2][3] = fmaf(f2, w.w, acc[2][3]);
        acc[3][0] = fmaf(f3, w.x, acc[3][0]); acc[3][1] = fmaf(f3, w.y, acc[3][1]);
        acc[3][2] = fmaf(f3, w.z, acc[3][2]); acc[3][3] = fmaf(f3, w.w, acc[3][3]);
    }

    #pragma unroll
    for (int i = 0; i < 4; ++i) {
        int gr = rbase + ty * 4 + i;
        if (gr < NN) {
            float s = rsqrtf((float)cnt[gr] + 1.0f);
            __half2 h0 = __floats2half2_rn(acc[i][0] * s, acc[i][1] * s);
            __half2 h1 = __floats2half2_rn(acc[i][2] * s, acc[i][3] * s);
            union { __half2 h[2]; uint2 u; } p;
            p.h[0] = h0; p.h[1] = h1;
            *reinterpret_cast<uint2*>(&y[gr * D + tx * 4]) = p.u;
        }
    }
}

// ---------------------------------------------------------------------------
// k_agg: out[c] = rsqrt(deg[c]) * (y[c] + sum_i y[csr[off[c]+i]]) + b
__global__ __launch_bounds__(256) void k_agg(const unsigned short* __restrict__ csr,
                                             const int* __restrict__ off,
                                             const int* __restrict__ cnt,
                                             const __half* __restrict__ y,
                                             const float* __restrict__ b,
                                             float* __restrict__ out) {
    const int lane = threadIdx.x & 63;
    const int grp  = lane >> 3;
    const int l8   = lane & 7;
    const int c    = blockIdx.x * (blockDim.x >> 6) + (threadIdx.x >> 6);
    if (c >= NN) return;

    const uint4* y16 = reinterpret_cast<const uint4*>(y);

    int s = off[c];
    int n = cnt[c];

    float acc[8] = {0.f, 0.f, 0.f, 0.f, 0.f, 0.f, 0.f, 0.f};

    auto addrow = [&](int r) {
        uint4 u = y16[r * 8 + l8];
        const __half2* h = reinterpret_cast<const __half2*>(&u);
        float2 f0 = __half22float2(h[0]);
        float2 f1 = __half22float2(h[1]);
        float2 f2 = __half22float2(h[2]);
        float2 f3 = __half22float2(h[3]);
        acc[0] += f0.x; acc[1] += f0.y; acc[2] += f1.x; acc[3] += f1.y;
        acc[4] += f2.x; acc[5] += f2.y; acc[6] += f3.x; acc[7] += f3.y;
    };

    if (grp == 0) addrow(c);
    for (int i = grp; i < n; i += 8) addrow(csr[s + i]);

    #pragma unroll
    for (int m = 8; m <= 32; m <<= 1) {
        #pragma unroll
        for (int j = 0; j < 8; ++j) acc[j] += __shfl_xor(acc[j], m);
    }

    if (grp == 0) {
        float sc = rsqrtf((float)n + 1.0f);
        const float4* b4 = reinterpret_cast<const float4*>(b);
        float4 bb0 = b4[l8 * 2], bb1 = b4[l8 * 2 + 1];
        float4 o0, o1;
        o0.x = acc[0] * sc + bb0.x;  o0.y = acc[1] * sc + bb0.y;
        o0.z = acc[2] * sc + bb0.z;  o0.w = acc[3] * sc + bb0.w;
        o1.x = acc[4] * sc + bb1.x;  o1.y = acc[5] * sc + bb1.y;
        o1.z = acc[6] * sc + bb1.z;  o1.w = acc[7] * sc + bb1.w;
        float4* out4 = reinterpret_cast<float4*>(out);
        out4[c * 16 + l8 * 2]     = o0;
        out4[c * 16 + l8 * 2 + 1] = o1;
    }
}

// ---------------------------------------------------------------------------
extern "C" void kernel_launch(void* const* d_in, const int* in_sizes, int n_in,
                              void* d_out, int out_size, void* d_ws, size_t ws_size,
                              hipStream_t stream) {
    const float* feat = (const float*)d_in[0];   // [NN, D]
    const float* W    = (const float*)d_in[1];   // [D, D]
    const float* b    = (const float*)d_in[2];   // [D]
    const int*   ei   = (const int*)d_in[3];     // [2, NE]
    const int*   row  = ei;                      // sources
    const int*   col  = ei + NE;                 // targets

    float* out = (float*)d_out;                  // [NN, D]

    // workspace layout (~12 MB)
    int*            H      = (int*)d_ws;                      // [65536]
    int*            bsum   = H + 65536;                       // [256] (pad 1024)
    int*            cnt    = bsum + 1024;                     // [65536]
    int*            off    = cnt + 65536;                     // [65536]
    unsigned int*   packed = (unsigned int*)(off + 65536);    // [NE]
    unsigned short* csr    = (unsigned short*)(packed + NE);  // [NE]
    __half*         y      = (__half*)(csr + NE);             // [NN*D], 16B-aligned

    k_hist  <<<NBUK, 256, 0, stream>>>(col, H);
    k_scanA <<<NBUK, 256, 0, stream>>>(H, bsum);
    k_bucket<<<NBUK, 256, 0, stream>>>(row, col, H, bsum, packed);
    k_csr   <<<NBUK, 256, 0, stream>>>(packed, bsum, off, cnt, csr);
    k_gemm  <<<(NN + 63) / 64, 256, 0, stream>>>(feat, W, cnt, y);
    k_agg   <<<(NN + 3) / 4, 256, 0, stream>>>(csr, off, cnt, y, b, out);
}